// Round 13
// baseline (93.269 us; speedup 1.0000x reference)
//
#include <hip/hip_runtime.h>
#include <math.h>

#ifndef __has_builtin
#define __has_builtin(x) 0
#endif

#define GRIDC  32          // cells per axis (256 px / 8 px)
#define NCELL  1024
#define CSHIFT 3           // 8 px cells
#define RAD    4           // +-4 cells => all nodes within 32 px included.
                           // RAD must stay 4 (see R8 note). R10: per-row circle
                           // pruning regressed (max-lane). R11: f16 packing
                           // regressed (VALU unpack > DS savings).
#define QCAP   128         // query slots/cell; Poisson(64) overflow ~5e-13 ->
                           // exact overflow list anyway.

// ws int map:
//   [0]            overflow cursor
//   [64, 64+1024)  per-cell query counters          (memset to 0, 8 KB total)
//   [2048, 2048+NCELL*QCAP*4)   qbuf: int4 {n,x,y,0} per query, cell-bucketed
//   [526336, +4*65536)          ovf:  int4 overflow queries
#define OFF_QCNT 64
#define OFF_QB   2048
#define OFF_OVF  (2048 + NCELL * QCAP * 4)
#define WS_NEED_INTS (OFF_OVF + 4 * 65536)

__device__ __forceinline__ float fast_exp2(float x) {
#if __has_builtin(__builtin_amdgcn_exp2f)
    return __builtin_amdgcn_exp2f(x);
#else
    return exp2f(x);
#endif
}

__device__ __forceinline__ int cell_of(int x, int y) {
    int cx = x >> CSHIFT; cx = cx < 0 ? 0 : (cx > GRIDC - 1 ? GRIDC - 1 : cx);
    int cy = y >> CSHIFT; cy = cy < 0 ? 0 : (cy > GRIDC - 1 ? GRIDC - 1 : cy);
    return (cy << 5) + cx;
}

// ---------------------------------------------------------------------------
// Bucket queries by cell. Order within a cell is nondeterministic but each
// query's own accumulation order (node order) is fixed -> output deterministic
// up to the usual fp tolerance.
// ---------------------------------------------------------------------------
__global__ __launch_bounds__(256) void scatter_q(const int* __restrict__ X,
                                                 int* __restrict__ wsI, int N) {
    int n = blockIdx.x * 256 + threadIdx.x;
    if (n >= N) return;
    int2 xy = ((const int2*)X)[n];
    int c = cell_of(xy.x, xy.y);
    int slot = atomicAdd(&wsI[OFF_QCNT + c], 1);
    int4 rec = make_int4(n, xy.x, xy.y, 0);
    if (slot < QCAP) {
        ((int4*)(wsI + OFF_QB))[c * QCAP + slot] = rec;
    } else {
        int o = atomicAdd(&wsI[0], 1);
        ((int4*)(wsI + OFF_OVF))[o] = rec;
    }
}

// ---------------------------------------------------------------------------
// 256 blocks x 512 thr (8 waves). Phase 1: every block bins all nodes into
// LDS (as R9: histogram + shfl scan + scatter, f32 records). Phase 2: wave w
// handles chunk id = blockIdx*8+w -> cell id/2, queries [64*(id&1), ...).
// ALL lanes of a wave share one cell => k0..k1 and sA[k]/sB[k] addresses are
// WAVE-UNIFORM: LDS reads broadcast (conflict-free), trip counts identical
// across lanes (no max-lane imbalance). Overflow queries: wave 7 grid-stride,
// per-lane divergent walk (count ~0, exactness only).
// LDS: 32K sA + 16K sB + 4.1K sst = 52.2 KB.
// ---------------------------------------------------------------------------
__global__ __launch_bounds__(512) void rbf_sorted(const int* __restrict__ wsI,
        const int* __restrict__ pat, const float* __restrict__ W2,
        const float* __restrict__ sig, float* __restrict__ out, int N, int P) {
    __shared__ float4 sA[2048];        // {px, py, s, w0}
    __shared__ float2 sB[2048];        // {w1, w2}
    __shared__ int    sst[NCELL + 1];
    __shared__ int    wsum[8];

    const int tid  = threadIdx.x;
    const int lane = tid & 63;
    const int wv   = tid >> 6;

    // ---- Phase 1a: zero counts ----
    for (int i = tid; i < NCELL + 1; i += 512) sst[i] = 0;
    __syncthreads();

    // ---- Phase 1b: histogram ----
    int cellr[4], slotr[4], xr[4], yr[4];
#pragma unroll
    for (int j = 0; j < 4; ++j) {
        int p = j * 512 + tid;
        cellr[j] = -1;
        if (p < P) {
            int2 xy = ((const int2*)pat)[p];
            xr[j] = xy.x; yr[j] = xy.y;
            int c = cell_of(xy.x, xy.y);
            cellr[j] = c;
            slotr[j] = atomicAdd(&sst[c], 1);
        }
    }
    __syncthreads();

    // ---- Phase 1c: exclusive scan (thread owns 2 cells) ----
    const int c0 = sst[2 * tid], c1 = sst[2 * tid + 1];
    int sum = c0 + c1;
    int incl = sum;
#pragma unroll
    for (int off = 1; off < 64; off <<= 1) {
        int t = __shfl_up(incl, off);
        if (lane >= off) incl += t;
    }
    if (lane == 63) wsum[wv] = incl;
    __syncthreads();
    int base = 0;
#pragma unroll
    for (int w = 0; w < 8; ++w) base += (w < wv) ? wsum[w] : 0;
    const int excl0 = base + incl - sum;
    __syncthreads();
    sst[2 * tid + 0] = excl0;
    sst[2 * tid + 1] = excl0 + c0;
    if (tid == 511) sst[NCELL] = excl0 + c0 + c1;
    __syncthreads();

    // ---- Phase 1d: scatter node records ----
#pragma unroll
    for (int j = 0; j < 4; ++j) {
        if (cellr[j] >= 0) {
            int p = j * 512 + tid;
            int pos = sst[cellr[j]] + slotr[j];
            sA[pos] = make_float4((float)xr[j], (float)yr[j],
                                  -0.7213475204444817f / sig[p], W2[p]);
            sB[pos] = make_float2(W2[P + p], W2[2 * P + p]);
        }
    }
    __syncthreads();

    // ---- Phase 2: one wave = one 64-query chunk of one cell ----
    const int chunk = blockIdx.x * 8 + wv;      // [0, 2048)
    const int cell  = chunk >> 1;
    const int qoff  = (chunk & 1) * 64;
    int qn = wsI[OFF_QCNT + cell];
    qn = qn > QCAP ? QCAP : qn;

    const int qi = qoff + lane;
    if (qi < qn) {
        int4 q = ((const int4*)(wsI + OFF_QB))[cell * QCAP + qi];
        const float xf = (float)q.y, yf = (float)q.z;
        const int cx = cell & (GRIDC - 1);
        const int cy = cell >> 5;
        const int x0 = cx - RAD < 0 ? 0 : cx - RAD;
        const int x1 = cx + RAD > GRIDC - 1 ? GRIDC - 1 : cx + RAD;
        float den = 0.f, a0 = 0.f, a1 = 0.f, a2 = 0.f;
#pragma unroll
        for (int r = 0; r < 9; ++r) {
            int gy = cy - RAD + r;
            if ((unsigned)gy >= GRIDC) continue;
            int row = gy << 5;
            int k0 = sst[row + x0];              // wave-uniform
            int k1 = sst[row + x1 + 1];          // wave-uniform
            for (int k = k0; k < k1; ++k) {      // uniform bounds, broadcast reads
                float4 a = sA[k];
                float2 b = sB[k];
                float dx = xf - a.x;
                float dy = yf - a.y;
                float rr = fast_exp2(fmaf(dy, dy, dx * dx) * a.z);
                den += rr;
                a0 = fmaf(rr, a.w, a0);
                a1 = fmaf(rr, b.x, a1);
                a2 = fmaf(rr, b.y, a2);
            }
        }
        int n = q.x;
        float inv = 1.0f / den;
        out[3 * n + 0] = a0 * inv;
        out[3 * n + 1] = a1 * inv;
        out[3 * n + 2] = a2 * inv;
    }

    // ---- overflow queries (exactness; expected count 0) ----
    if (wv == 7) {
        int ovfc = wsI[0];
        for (int o = blockIdx.x * 64 + lane; o < ovfc; o += 256 * 64) {
            int4 q = ((const int4*)(wsI + OFF_OVF))[o];
            const float xf = (float)q.y, yf = (float)q.z;
            int cx = q.y >> CSHIFT; cx = cx < 0 ? 0 : (cx > GRIDC - 1 ? GRIDC - 1 : cx);
            int cy = q.z >> CSHIFT; cy = cy < 0 ? 0 : (cy > GRIDC - 1 ? GRIDC - 1 : cy);
            const int x0 = cx - RAD < 0 ? 0 : cx - RAD;
            const int x1 = cx + RAD > GRIDC - 1 ? GRIDC - 1 : cx + RAD;
            float den = 0.f, a0 = 0.f, a1 = 0.f, a2 = 0.f;
            for (int r = 0; r < 9; ++r) {
                int gy = cy - RAD + r;
                if ((unsigned)gy >= GRIDC) continue;
                int row = gy << 5;
                int k0 = sst[row + x0];
                int k1 = sst[row + x1 + 1];
                for (int k = k0; k < k1; ++k) {
                    float4 a = sA[k];
                    float2 b = sB[k];
                    float dx = xf - a.x;
                    float dy = yf - a.y;
                    float rr = fast_exp2(fmaf(dy, dy, dx * dx) * a.z);
                    den += rr;
                    a0 = fmaf(rr, a.w, a0);
                    a1 = fmaf(rr, b.x, a1);
                    a2 = fmaf(rr, b.y, a2);
                }
            }
            int n = q.x;
            float inv = 1.0f / den;
            out[3 * n + 0] = a0 * inv;
            out[3 * n + 1] = a1 * inv;
            out[3 * n + 2] = a2 * inv;
        }
    }
}

// ---------------------------------------------------------------------------
// Generic fallback (unexpected sizes): brute-force N x P sweep.
// ---------------------------------------------------------------------------
__global__ void pack_nodes(const int* __restrict__ pat, const float* __restrict__ W2,
                           const float* __restrict__ sigmaSq, float* __restrict__ nodes,
                           int P) {
    int p = blockIdx.x * blockDim.x + threadIdx.x;
    if (p >= P) return;
    float* q = nodes + 8 * (size_t)p;
    q[0] = (float)pat[2 * p];
    q[1] = (float)pat[2 * p + 1];
    q[2] = -0.7213475204444817f / sigmaSq[p];
    q[3] = W2[p];
    q[4] = W2[P + p];
    q[5] = W2[2 * P + p];
    q[6] = 0.0f;
    q[7] = 0.0f;
}

__global__ __launch_bounds__(256) void rbf_main_dyn(const int* __restrict__ X,
                                                    const float* __restrict__ nodes,
                                                    float* __restrict__ outp,
                                                    int N, int P) {
    int n = blockIdx.x * 256 + threadIdx.x;
    if (n >= N) return;
    float xn = (float)X[2 * n], yn = (float)X[2 * n + 1];
    float den = 0.f, a0 = 0.f, a1 = 0.f, a2 = 0.f;
    for (int j = 0; j < P; ++j) {
        const float* q = nodes + (size_t)j * 8;
        float dx = xn - q[0], dy = yn - q[1];
        float r = fast_exp2(fmaf(dy, dy, dx * dx) * q[2]);
        den += r;
        a0 = fmaf(r, q[3], a0);
        a1 = fmaf(r, q[4], a1);
        a2 = fmaf(r, q[5], a2);
    }
    outp[3 * n + 0] = a0 / den;
    outp[3 * n + 1] = a1 / den;
    outp[3 * n + 2] = a2 / den;
}

extern "C" void kernel_launch(void* const* d_in, const int* in_sizes, int n_in,
                              void* d_out, int out_size, void* d_ws, size_t ws_size,
                              hipStream_t stream) {
    const int*   X   = (const int*)d_in[0];
    const int*   pat = (const int*)d_in[1];
    const float* W2  = (const float*)d_in[2];
    const float* sig = (const float*)d_in[3];
    float*       out = (float*)d_out;

    const int N = in_sizes[0] / 2;
    const int P = in_sizes[3];

    int* wsI = (int*)d_ws;

    if (P <= 2048 && out_size == 3 * N && N <= 65536 &&
        ws_size >= WS_NEED_INTS * sizeof(int)) {
        hipMemsetAsync(d_ws, 0, 2048 * sizeof(int), stream);   // cursor + counters
        scatter_q<<<dim3((N + 255) / 256), dim3(256), 0, stream>>>(X, wsI, N);
        rbf_sorted<<<dim3(256), dim3(512), 0, stream>>>(wsI, pat, W2, sig, out, N, P);
    } else {
        float* nodes = (float*)d_ws;
        pack_nodes<<<dim3((P + 255) / 256), dim3(256), 0, stream>>>(pat, W2, sig, nodes, P);
        rbf_main_dyn<<<dim3((N + 255) / 256), dim3(256), 0, stream>>>(X, nodes, out, N, P);
    }
}

// Round 14
// 73.154 us; speedup vs baseline: 1.2750x; 1.2750x over previous
//
#include <hip/hip_runtime.h>
#include <math.h>

#ifndef __has_builtin
#define __has_builtin(x) 0
#endif

#define GRIDC  32          // cells per axis (256 px / 8 px)
#define NCELL  1024
#define CSHIFT 3           // 8 px cells
#define RAD    4           // +-4 cells => all nodes within 32 px included.
                           // RAD must stay 4 (worst-case den analysis, R8).
// Negative results (do not re-add):
//   R10: per-row circle pruning  -> +2.9 us (wave cost = max over lanes)
//   R11: f16-packed 16B records  -> +1.4 us (VALU unpack > DS savings)
//   R12: global query cell-sort  -> +21 us (global atomics + extra dispatches)

__device__ __forceinline__ float fast_exp2(float x) {
#if __has_builtin(__builtin_amdgcn_exp2f)
    return __builtin_amdgcn_exp2f(x);
#else
    return exp2f(x);
#endif
}

__device__ __forceinline__ int cell_of(int x, int y) {
    int cx = x >> CSHIFT; cx = cx < 0 ? 0 : (cx > GRIDC - 1 ? GRIDC - 1 : cx);
    int cy = y >> CSHIFT; cy = cy < 0 ? 0 : (cy > GRIDC - 1 ? GRIDC - 1 : cy);
    return (cy << 5) + cx;
}

// ---------------------------------------------------------------------------
// Single fused kernel (best known, R9 = 72.1 us total). 512 threads,
// 128 queries (4 threads/query).
//   Phase 1: bin ALL nodes (<=2048) into LDS: histogram (LDS atomics) ->
//            shfl wave-scan (2 barriers) -> scatter cell-sorted records.
//   Phase 2: thread quarter walks window rows [9q/4, 9(q+1)/4) with the inner
//            node loop software-pipelined (register prefetch of node k+1).
// LDS ~59.5 KB -> 2 blocks/CU; grid 512 blocks, 16 waves/CU.
// ---------------------------------------------------------------------------
__global__ __launch_bounds__(512) void rbf_fused(const int* __restrict__ X,
        const int* __restrict__ pat, const float* __restrict__ W2,
        const float* __restrict__ sig, float* __restrict__ out, int N, int P) {
    __shared__ float4 sA[2048];        // {px, py, s, w0}   32 KB
    __shared__ float2 sB[2048];        // {w1, w2}          16 KB
    __shared__ int    sst[NCELL + 1];  // counts -> starts   4.1 KB
    __shared__ float4 accb[3 * 128];   // quarter partials   6 KB
    __shared__ int    wsum[8];

    const int tid  = threadIdx.x;
    const int lane = tid & 63;
    const int wv   = tid >> 6;

    // ---- Phase 1a: zero counts ----
    for (int i = tid; i < NCELL + 1; i += 512) sst[i] = 0;
    __syncthreads();

    // ---- Phase 1b: histogram (up to 4 nodes/thread, coalesced) ----
    int cellr[4], slotr[4], xr[4], yr[4];
#pragma unroll
    for (int j = 0; j < 4; ++j) {
        int p = j * 512 + tid;
        cellr[j] = -1;
        if (p < P) {
            int2 xy = ((const int2*)pat)[p];
            xr[j] = xy.x; yr[j] = xy.y;
            int c = cell_of(xy.x, xy.y);
            cellr[j] = c;
            slotr[j] = atomicAdd(&sst[c], 1);
        }
    }
    __syncthreads();

    // ---- Phase 1c: exclusive scan of 1024 counts (thread owns 2 cells) ----
    const int c0 = sst[2 * tid], c1 = sst[2 * tid + 1];
    int sum = c0 + c1;
    int incl = sum;
#pragma unroll
    for (int off = 1; off < 64; off <<= 1) {
        int t = __shfl_up(incl, off);
        if (lane >= off) incl += t;
    }
    if (lane == 63) wsum[wv] = incl;
    __syncthreads();
    int base = 0;
#pragma unroll
    for (int w = 0; w < 8; ++w) base += (w < wv) ? wsum[w] : 0;
    const int excl0 = base + incl - sum;        // exclusive start of cell 2*tid
    __syncthreads();                            // all reads of wsum done
    sst[2 * tid + 0] = excl0;
    sst[2 * tid + 1] = excl0 + c0;
    if (tid == 511) sst[NCELL] = excl0 + c0 + c1;
    __syncthreads();

    // ---- Phase 1d: scatter node records into cell-sorted LDS ----
#pragma unroll
    for (int j = 0; j < 4; ++j) {
        if (cellr[j] >= 0) {
            int p = j * 512 + tid;
            int pos = sst[cellr[j]] + slotr[j];
            sA[pos] = make_float4((float)xr[j], (float)yr[j],
                                  -0.7213475204444817f / sig[p], W2[p]);
            sB[pos] = make_float2(W2[P + p], W2[2 * P + p]);
        }
    }
    __syncthreads();

    // ---- Phase 2: RBF, 4 threads per query (window rows split 2/2/2/3) ----
    const int quarter = tid >> 7;          // 0..3
    const int qi      = tid & 127;
    const int n       = blockIdx.x * 128 + qi;
    const bool act    = n < N;

    float den = 0.f, acc0 = 0.f, acc1 = 0.f, acc2 = 0.f;
    if (act) {
        int2 xy = ((const int2*)X)[n];
        const float xf = (float)xy.x, yf = (float)xy.y;
        int cx = xy.x >> CSHIFT; cx = cx < 0 ? 0 : (cx > GRIDC - 1 ? GRIDC - 1 : cx);
        int cy = xy.y >> CSHIFT; cy = cy < 0 ? 0 : (cy > GRIDC - 1 ? GRIDC - 1 : cy);
        const int x0 = cx - RAD < 0 ? 0 : cx - RAD;
        const int x1 = cx + RAD > GRIDC - 1 ? GRIDC - 1 : cx + RAD;
        const int r0 = (9 * quarter) >> 2;         // 0,2,4,6
        const int r1 = (9 * (quarter + 1)) >> 2;   // 2,4,6,9
        for (int r = r0; r < r1; ++r) {
            int gy = cy - RAD + r;
            if ((unsigned)gy >= GRIDC) continue;
            int row = gy << 5;
            int k0 = sst[row + x0];
            int k1 = sst[row + x1 + 1];
            if (k0 >= k1) continue;
            // software pipeline: registers hold node k; prefetch k+1 (clamped)
            float4 a = sA[k0];
            float2 b = sB[k0];
            for (int k = k0; k < k1; ++k) {
                int kn = k + 1 < k1 ? k + 1 : k;
                float4 an = sA[kn];
                float2 bn = sB[kn];
                float dx = xf - a.x;
                float dy = yf - a.y;
                float rr = fast_exp2(fmaf(dy, dy, dx * dx) * a.z);
                den  += rr;
                acc0 = fmaf(rr, a.w, acc0);
                acc1 = fmaf(rr, b.x, acc1);
                acc2 = fmaf(rr, b.y, acc2);
                a = an; b = bn;
            }
        }
    }

    if (quarter) accb[(quarter - 1) * 128 + qi] = make_float4(den, acc0, acc1, acc2);
    __syncthreads();
    if (quarter == 0 && act) {
#pragma unroll
        for (int w = 0; w < 3; ++w) {
            float4 u = accb[w * 128 + qi];
            den += u.x; acc0 += u.y; acc1 += u.z; acc2 += u.w;
        }
        float inv = 1.0f / den;
        out[3 * n + 0] = acc0 * inv;
        out[3 * n + 1] = acc1 * inv;
        out[3 * n + 2] = acc2 * inv;
    }
}

// ---------------------------------------------------------------------------
// Generic fallback (unexpected sizes): brute-force N x P sweep.
// ---------------------------------------------------------------------------
__global__ void pack_nodes(const int* __restrict__ pat, const float* __restrict__ W2,
                           const float* __restrict__ sigmaSq, float* __restrict__ nodes,
                           int P) {
    int p = blockIdx.x * blockDim.x + threadIdx.x;
    if (p >= P) return;
    float* q = nodes + 8 * (size_t)p;
    q[0] = (float)pat[2 * p];
    q[1] = (float)pat[2 * p + 1];
    q[2] = -0.7213475204444817f / sigmaSq[p];
    q[3] = W2[p];
    q[4] = W2[P + p];
    q[5] = W2[2 * P + p];
    q[6] = 0.0f;
    q[7] = 0.0f;
}

__global__ __launch_bounds__(256) void rbf_main_dyn(const int* __restrict__ X,
                                                    const float* __restrict__ nodes,
                                                    float* __restrict__ outp,
                                                    int N, int P) {
    int n = blockIdx.x * 256 + threadIdx.x;
    if (n >= N) return;
    float xn = (float)X[2 * n], yn = (float)X[2 * n + 1];
    float den = 0.f, a0 = 0.f, a1 = 0.f, a2 = 0.f;
    for (int j = 0; j < P; ++j) {
        const float* q = nodes + (size_t)j * 8;
        float dx = xn - q[0], dy = yn - q[1];
        float r = fast_exp2(fmaf(dy, dy, dx * dx) * q[2]);
        den += r;
        a0 = fmaf(r, q[3], a0);
        a1 = fmaf(r, q[4], a1);
        a2 = fmaf(r, q[5], a2);
    }
    outp[3 * n + 0] = a0 / den;
    outp[3 * n + 1] = a1 / den;
    outp[3 * n + 2] = a2 / den;
}

extern "C" void kernel_launch(void* const* d_in, const int* in_sizes, int n_in,
                              void* d_out, int out_size, void* d_ws, size_t ws_size,
                              hipStream_t stream) {
    const int*   X   = (const int*)d_in[0];
    const int*   pat = (const int*)d_in[1];
    const float* W2  = (const float*)d_in[2];
    const float* sig = (const float*)d_in[3];
    float*       out = (float*)d_out;

    const int N = in_sizes[0] / 2;
    const int P = in_sizes[3];

    if (P <= 2048 && out_size == 3 * N) {
        rbf_fused<<<dim3((N + 127) / 128), dim3(512), 0, stream>>>(
            X, pat, W2, sig, out, N, P);
    } else {
        float* nodes = (float*)d_ws;
        pack_nodes<<<dim3((P + 255) / 256), dim3(256), 0, stream>>>(pat, W2, sig, nodes, P);
        rbf_main_dyn<<<dim3((N + 255) / 256), dim3(256), 0, stream>>>(X, nodes, out, N, P);
    }
}